// Round 3
// baseline (154.072 us; speedup 1.0000x reference)
//
#include <hip/hip_runtime.h>
#include <stdint.h>

// ---------- types ----------
typedef __attribute__((ext_vector_type(8))) short bf16x8;
typedef __attribute__((ext_vector_type(4))) float f32x4;

// ---------- helpers ----------
__device__ __forceinline__ unsigned short f2bf(float f) {
  union { float f; unsigned int u; } un; un.f = f;
  unsigned int r = un.u + 0x7fffu + ((un.u >> 16) & 1u);
  return (unsigned short)(r >> 16);
}

__device__ __forceinline__ float tanh_fast(float x) {
  x = fminf(15.f, fmaxf(-15.f, x));
  float e = __expf(2.f * x);
  return (e - 1.f) / (e + 1.f);
}

// async global->LDS, 16B per lane. lds dest must be wave-uniform base.
__device__ __forceinline__ void gload_lds16(const void* g, void* l) {
  __builtin_amdgcn_global_load_lds(
      (const __attribute__((address_space(1))) unsigned int*)(unsigned long long)g,
      (__attribute__((address_space(3))) unsigned int*)(unsigned int)(unsigned long long)l,
      16, 0, 0);
}

// ---------- convert kernels ----------
__global__ __launch_bounds__(256) void cvt_y_kernel(
    const float* __restrict__ x, unsigned short* __restrict__ y, int n4) {
  int i = blockIdx.x * blockDim.x + threadIdx.x;
  if (i < n4) {
    const float4 v = reinterpret_cast<const float4*>(x)[i];
    ushort4 o;
    o.x = f2bf(v.x); o.y = f2bf(v.y); o.z = f2bf(v.z); o.w = f2bf(v.w);
    reinterpret_cast<ushort4*>(y)[i] = o;
  }
}

// Wt[c][r] = bf16(W[r][c]); W is [R][ldW], use first C cols. Wt row-major [C][R].
__global__ __launch_bounds__(256) void cvt_transpose_kernel(
    const float* __restrict__ W, unsigned short* __restrict__ Wt,
    int R, int C, int ldW) {
  int i = blockIdx.x * blockDim.x + threadIdx.x;
  if (i < R * C) {
    int c = i / R, r = i - c * R;
    Wt[(size_t)c * R + r] = f2bf(W[(size_t)r * ldW + c]);
  }
}

// ---------- p0 kernel (null-token path) ----------
__global__ __launch_bounds__(512) void p0_kernel(
    const float* __restrict__ ynull, const float* __restrict__ W_trans,
    const float* __restrict__ b_trans, const float* __restrict__ W_p0,
    const float* __restrict__ b_p0, float* __restrict__ p0buf) {
  __shared__ float red[512];
  const int hh = threadIdx.x;
  float acc = 0.f;
  for (int e = 0; e < 512; ++e) acc = fmaf(ynull[e], W_trans[(size_t)e * 512 + hh], acc);
  const float ts = tanhf(acc + b_trans[hh]);
  red[hh] = ts * W_p0[hh];
  __syncthreads();
  for (int s = 256; s > 0; s >>= 1) {
    if (hh < s) red[hh] += red[hh + s];
    __syncthreads();
  }
  if (hh == 0) {
    const float z = red[0] + b_p0[0];
    const float p0 = 1.f / (1.f + __expf(-z));
    p0buf[0] = p0;
    p0buf[1] = 1.f - p0;
  }
}

// ---------- bf16 MFMA GEMM: C = epi(A @ Bt^T + bias) ----------
template <int EPI>
__global__ __launch_bounds__(256, 2) void gemm_tt(
    const unsigned short* __restrict__ A, const unsigned short* __restrict__ Bt,
    const float* __restrict__ bias, void* __restrict__ Cout,
    int M, int N, int K) {
  __shared__ unsigned short sA[128 * 32];
  __shared__ unsigned short sB[128 * 32];
  const int tid = threadIdx.x;
  const int lane = tid & 63;
  const int wave = tid >> 6;
  const int wr = wave >> 1, wc = wave & 1;
  const int m0 = blockIdx.x * 128, n0 = blockIdx.y * 128;

  f32x4 acc[4][4] = {};

  const int srow = lane >> 2;
  const int scol = (lane & 3) * 8;
  const int c0 = wave * 2, c1 = wave * 2 + 1;
  const unsigned short* Ar0 = A + (size_t)(m0 + c0 * 16 + srow) * K + scol;
  const unsigned short* Ar1 = A + (size_t)(m0 + c1 * 16 + srow) * K + scol;
  const unsigned short* Br0 = Bt + (size_t)(n0 + c0 * 16 + srow) * K + scol;
  const unsigned short* Br1 = Bt + (size_t)(n0 + c1 * 16 + srow) * K + scol;

  for (int kk = 0; kk < K; kk += 32) {
    __syncthreads();
    gload_lds16(Ar0 + kk, &sA[c0 * 512]);
    gload_lds16(Ar1 + kk, &sA[c1 * 512]);
    gload_lds16(Br0 + kk, &sB[c0 * 512]);
    gload_lds16(Br1 + kk, &sB[c1 * 512]);
    __syncthreads();
    bf16x8 af[4], bfr[4];
#pragma unroll
    for (int mi = 0; mi < 4; ++mi)
      af[mi] = *reinterpret_cast<const bf16x8*>(
          &sA[(wr * 64 + mi * 16 + (lane & 15)) * 32 + (lane >> 4) * 8]);
#pragma unroll
    for (int ni = 0; ni < 4; ++ni)
      bfr[ni] = *reinterpret_cast<const bf16x8*>(
          &sB[(wc * 64 + ni * 16 + (lane & 15)) * 32 + (lane >> 4) * 8]);
#pragma unroll
    for (int mi = 0; mi < 4; ++mi)
#pragma unroll
      for (int ni = 0; ni < 4; ++ni)
        acc[mi][ni] = __builtin_amdgcn_mfma_f32_16x16x32_bf16(
            af[mi], bfr[ni], acc[mi][ni], 0, 0, 0);
  }

  const int crow0 = m0 + wr * 64 + (lane >> 4) * 4;
  const int ccol0 = n0 + wc * 64 + (lane & 15);
#pragma unroll
  for (int mi = 0; mi < 4; ++mi) {
#pragma unroll
    for (int ni = 0; ni < 4; ++ni) {
      const int gcol = ccol0 + ni * 16;
      const float bv = bias[gcol];
#pragma unroll
      for (int r = 0; r < 4; ++r) {
        const int grow = crow0 + mi * 16 + r;
        const float v = acc[mi][ni][r] + bv;
        if constexpr (EPI == 0) {
          ((unsigned short*)Cout)[(size_t)grow * N + gcol] = f2bf(tanh_fast(v));
        } else {
          ((float*)Cout)[(size_t)grow * N + gcol] = v;
        }
      }
    }
  }
}

// ---------- windowed softmax -> jw [B][128][128] bf16 ----------
__global__ __launch_bounds__(256) void wsoftmax_kernel(
    const float* __restrict__ logits, const float* __restrict__ p0buf,
    unsigned short* __restrict__ jwout) {
  const int lane = threadIdx.x & 63;
  const int wave = threadIdx.x >> 6;
  const int row = blockIdx.x * 4 + wave;  // row = b*128 + i, < 32768
  const int i = row & 127;
  const float* lrow = logits + (size_t)row * 256 + (128 - i);
  const float v0 = lrow[lane];
  const float v1 = lrow[lane + 64];
  float mx = fmaxf(v0, v1);
#pragma unroll
  for (int off = 32; off > 0; off >>= 1) mx = fmaxf(mx, __shfl_xor(mx, off));
  const float e0 = __expf(v0 - mx);
  const float e1 = __expf(v1 - mx);
  float s = e0 + e1;
#pragma unroll
  for (int off = 32; off > 0; off >>= 1) s += __shfl_xor(s, off);
  const float scale = p0buf[1] / s;  // (1-p0)/sum
  unsigned short* orow = jwout + (size_t)row * 128;
  orow[lane] = f2bf(e0 * scale);
  orow[lane + 64] = f2bf(e1 * scale);
}

// ---------- emission repack: epack[b][t][half*128+m*8+nt] ----------
//   = emission[b][half*128+nt*16+m][t] * (half ? p0 : 1)
// Coalesced writes; scattered reads are L2-deduped (each 64B line reused 16x).
__global__ __launch_bounds__(256) void etrans_kernel(
    const float* __restrict__ emission, const float* __restrict__ p0buf,
    float* __restrict__ epack) {
  const int blk = blockIdx.x;      // b*64 + t
  const int b = blk >> 6, t = blk & 63;
  const int j = threadIdx.x;       // 0..255
  const int half = j >> 7, m = (j & 127) >> 3, nt = j & 7;
  const int k = half * 128 + nt * 16 + m;
  float v = emission[(size_t)b * 16384 + (size_t)k * 64 + t];
  if (half) v *= p0buf[0];
  epack[(size_t)blk * 256 + j] = v;
}

// ---------- HMM forward recursion, MFMA matvec, 1 wave per batch ----------
__global__ __launch_bounds__(64, 1) void forward_hmm_mfma(
    const unsigned short* __restrict__ jwb,   // [B][128][128] bf16
    const float* __restrict__ epack,          // [B][64][256] repacked
    const float* __restrict__ emission,       // [B][256][64] original (t=0 init)
    const int* __restrict__ slen_p, const int* __restrict__ tlen_p,
    float* __restrict__ out) {
  __shared__ __align__(16) unsigned short gl16[128];  // g as bf16
  const int b = blockIdx.x;
  const int l = threadIdx.x;   // 0..63
  const int m = l & 15;
  const int q = l >> 4;

  // ---- build jw B-frags: bfr[kt][nt] elem j = jw[kt*32 + q*8 + j][nt*16 + m]
  const unsigned short* jwt = jwb + (size_t)b * 16384;
  bf16x8 bfr[4][8];
#pragma unroll
  for (int kt = 0; kt < 4; ++kt) {
    const int r0 = kt * 32 + q * 8;
#pragma unroll
    for (int nt = 0; nt < 8; ++nt) {
      const int c = nt * 16 + m;
      bf16x8 v;
#pragma unroll
      for (int j = 0; j < 8; ++j) v[j] = (short)jwt[(size_t)(r0 + j) * 128 + c];
      bfr[kt][nt] = v;
    }
  }

  const int S = slen_p[b];
  const int T = tlen_p[b];
  const float* ep = epack + (size_t)b * 16384;       // [64][256]
  const float* eb = emission + (size_t)b * 16384;    // [256][64]

  // ---- init g0[k] = e[k,0] + e[128+k,0] (unscaled, from original layout)
  float gown[8];
#pragma unroll
  for (int nt = 0; nt < 8; ++nt) {
    const int k = nt * 16 + m;
    gown[nt] = eb[(size_t)k * 64] + eb[(size_t)(k + 128) * 64];
  }
  // publish to LDS as bf16 (each q-group writes its 2 nt's; all groups identical)
  gl16[(2 * q) * 16 + m]     = f2bf(gown[2 * q]);
  gl16[(2 * q + 1) * 16 + m] = f2bf(gown[2 * q + 1]);

  // ---- prefetch e for t=1 (broadcast across q-groups)
  float4 pe0a, pe0b, pe1a, pe1b;
  {
    const float4* p0v = reinterpret_cast<const float4*>(ep + 256 + m * 8);
    const float4* p1v = reinterpret_cast<const float4*>(ep + 256 + 128 + m * 8);
    pe0a = p0v[0]; pe0b = p0v[1];
    pe1a = p1v[0]; pe1b = p1v[1];
  }

  for (int t = 1; t < S; ++t) {
    const float e0[8]  = {pe0a.x, pe0a.y, pe0a.z, pe0a.w, pe0b.x, pe0b.y, pe0b.z, pe0b.w};
    const float e1p[8] = {pe1a.x, pe1a.y, pe1a.z, pe1a.w, pe1b.x, pe1b.y, pe1b.z, pe1b.w};
    // self-term (off the MFMA critical path; e1p already includes p0)
    float h[8];
#pragma unroll
    for (int nt = 0; nt < 8; ++nt) h[nt] = gown[nt] * e1p[nt];
    // prefetch t+1
    {
      const int tn = (t + 1 < S) ? t + 1 : t;
      const float4* p0v = reinterpret_cast<const float4*>(ep + (size_t)tn * 256 + m * 8);
      const float4* p1v = reinterpret_cast<const float4*>(ep + (size_t)tn * 256 + 128 + m * 8);
      pe0a = p0v[0]; pe0b = p0v[1];
      pe1a = p1v[0]; pe1b = p1v[1];
    }
    // A-frags: g octets from LDS (bf16, conflict-free broadcast reads)
    bf16x8 af[4];
#pragma unroll
    for (int kt = 0; kt < 4; ++kt)
      af[kt] = *reinterpret_cast<const bf16x8*>(&gl16[kt * 32 + q * 8]);
    // matvec on the matrix pipe: 8 n-tiles x 4 chained k-tiles
    f32x4 acc[8];
#pragma unroll
    for (int nt = 0; nt < 8; ++nt) {
      f32x4 a = __builtin_amdgcn_mfma_f32_16x16x32_bf16(
          af[0], bfr[0][nt], (f32x4){0.f, 0.f, 0.f, 0.f}, 0, 0, 0);
      a = __builtin_amdgcn_mfma_f32_16x16x32_bf16(af[1], bfr[1][nt], a, 0, 0, 0);
      a = __builtin_amdgcn_mfma_f32_16x16x32_bf16(af[2], bfr[2][nt], a, 0, 0, 0);
      acc[nt] = __builtin_amdgcn_mfma_f32_16x16x32_bf16(af[3], bfr[3][nt], a, 0, 0, 0);
    }
    // g' = dot*e0 + g*p0*e1 ; publish next g to LDS
#pragma unroll
    for (int nt = 0; nt < 8; ++nt) gown[nt] = fmaf(acc[nt][0], e0[nt], h[nt]);
    gl16[(2 * q) * 16 + m]     = f2bf(gown[2 * q]);
    gl16[(2 * q + 1) * 16 + m] = f2bf(gown[2 * q + 1]);
  }

  // masked sum over k<T, reduce across the 16 m-lanes (q-groups identical)
  float val = 0.f;
#pragma unroll
  for (int nt = 0; nt < 8; ++nt)
    if (nt * 16 + m < T) val += gown[nt];
#pragma unroll
  for (int off = 1; off < 16; off <<= 1) val += __shfl_xor(val, off);
  if (l == 0) out[b] = logf(val + 1e-29f);
}

// ---------- launch ----------
extern "C" void kernel_launch(void* const* d_in, const int* in_sizes, int n_in,
                              void* d_out, int out_size, void* d_ws, size_t ws_size,
                              hipStream_t stream) {
  const float* y_hidden = (const float*)d_in[0];   // [256,128,512]
  const float* y_null   = (const float*)d_in[1];   // [1,1,512]
  const float* W_trans  = (const float*)d_in[2];   // [512,512]
  const float* b_trans  = (const float*)d_in[3];   // [512]
  const float* W_jump   = (const float*)d_in[4];   // [512,257]
  const float* b_jump   = (const float*)d_in[5];   // [257]
  const float* W_p0     = (const float*)d_in[6];   // [512,1]
  const float* b_p0     = (const float*)d_in[7];   // [1]
  const float* emission = (const float*)d_in[8];   // [256,256,64]
  const int* slen = (const int*)d_in[9];
  const int* tlen = (const int*)d_in[10];
  float* out = (float*)d_out;

  char* ws = (char*)d_ws;
  unsigned short* a16   = (unsigned short*)ws;               // 33,554,432 B
  float* logits         = (float*)ws;                        // alias a16 (dead after GEMM1)
  float* epack          = (float*)ws;                        // alias logits (dead after wsoftmax); 16 MB
  unsigned short* ts16  = (unsigned short*)(ws + 33554432);  // 33,554,432 B
  unsigned short* wt16t = (unsigned short*)(ws + 67108864);  // 524,288 B
  unsigned short* wj16t = (unsigned short*)(ws + 67633152);  // 262,144 B
  float* p0buf          = (float*)(ws + 67895296);           // 256 B
  unsigned short* jwb16 = (unsigned short*)(ws + 67895552);  // 8,388,608 B

  cvt_y_kernel<<<dim3(16384), dim3(256), 0, stream>>>(y_hidden, a16, 16777216 / 4);
  cvt_transpose_kernel<<<dim3((512 * 512 + 255) / 256), dim3(256), 0, stream>>>(
      W_trans, wt16t, 512, 512, 512);
  cvt_transpose_kernel<<<dim3((512 * 256 + 255) / 256), dim3(256), 0, stream>>>(
      W_jump, wj16t, 512, 256, 257);
  p0_kernel<<<dim3(1), dim3(512), 0, stream>>>(y_null, W_trans, b_trans, W_p0, b_p0, p0buf);

  gemm_tt<0><<<dim3(256, 4), dim3(256), 0, stream>>>(a16, wt16t, b_trans, (void*)ts16,
                                                     32768, 512, 512);
  gemm_tt<1><<<dim3(256, 2), dim3(256), 0, stream>>>(ts16, wj16t, b_jump, (void*)logits,
                                                     32768, 256, 512);
  wsoftmax_kernel<<<dim3(8192), dim3(256), 0, stream>>>(logits, p0buf, jwb16);
  // repack emission AFTER wsoftmax (epack aliases the now-dead logits buffer)
  etrans_kernel<<<dim3(256 * 64), dim3(256), 0, stream>>>(emission, p0buf, epack);
  forward_hmm_mfma<<<dim3(256), dim3(64), 0, stream>>>(jwb16, epack, emission,
                                                       slen, tlen, out);
}

// Round 5
// 119.417 us; speedup vs baseline: 1.2902x; 1.2902x over previous
//
#include <hip/hip_runtime.h>
#include <stdint.h>

// ---------- types ----------
typedef __attribute__((ext_vector_type(8))) short bf16x8;
typedef __attribute__((ext_vector_type(4))) float f32x4;

// ---------- helpers ----------
__device__ __forceinline__ unsigned short f2bf(float f) {
  union { float f; unsigned int u; } un; un.f = f;
  unsigned int r = un.u + 0x7fffu + ((un.u >> 16) & 1u);
  return (unsigned short)(r >> 16);
}

__device__ __forceinline__ float tanh_fast(float x) {
  x = fminf(15.f, fmaxf(-15.f, x));
  float e = __expf(2.f * x);
  return (e - 1.f) / (e + 1.f);
}

__device__ __forceinline__ unsigned int cvt_pk_bf16(float lo, float hi) {
  unsigned int r;
  asm("v_cvt_pk_bf16_f32 %0, %1, %2" : "=v"(r) : "v"(lo), "v"(hi));
  return r;
}

// async global->LDS, 16B per lane. lds dest must be wave-uniform base.
__device__ __forceinline__ void gload_lds16(const void* g, void* l) {
  __builtin_amdgcn_global_load_lds(
      (const __attribute__((address_space(1))) unsigned int*)(unsigned long long)g,
      (__attribute__((address_space(3))) unsigned int*)(unsigned int)(unsigned long long)l,
      16, 0, 0);
}

// Wt[c][r] = bf16(W[r][c]); W is [R][ldW], use first C cols. Wt row-major [C][R].
__global__ __launch_bounds__(256) void cvt_transpose_kernel(
    const float* __restrict__ W, unsigned short* __restrict__ Wt,
    int R, int C, int ldW) {
  int i = blockIdx.x * blockDim.x + threadIdx.x;
  if (i < R * C) {
    int c = i / R, r = i - c * R;
    Wt[(size_t)c * R + r] = f2bf(W[(size_t)r * ldW + c]);
  }
}

// ---------- p0 kernel (null-token path) ----------
__global__ __launch_bounds__(512) void p0_kernel(
    const float* __restrict__ ynull, const float* __restrict__ W_trans,
    const float* __restrict__ b_trans, const float* __restrict__ W_p0,
    const float* __restrict__ b_p0, float* __restrict__ p0buf) {
  __shared__ float red[512];
  const int hh = threadIdx.x;
  float acc = 0.f;
  for (int e = 0; e < 512; ++e) acc = fmaf(ynull[e], W_trans[(size_t)e * 512 + hh], acc);
  const float ts = tanhf(acc + b_trans[hh]);
  red[hh] = ts * W_p0[hh];
  __syncthreads();
  for (int s = 256; s > 0; s >>= 1) {
    if (hh < s) red[hh] += red[hh + s];
    __syncthreads();
  }
  if (hh == 0) {
    const float z = red[0] + b_p0[0];
    const float p0 = 1.f / (1.f + __expf(-z));
    p0buf[0] = p0;
    p0buf[1] = 1.f - p0;
  }
}

// ---------- GEMM1: C = tanh(Af32 @ Bt^T + bias) -> bf16 ----------
// A [M,K] f32 row-major (converted to bf16 on the fly during staging);
// Bt [N,K] bf16 row-major. 128x128 tile, BK=32, 4 waves.
__global__ __launch_bounds__(256, 2) void gemm_af32(
    const float* __restrict__ A, const unsigned short* __restrict__ Bt,
    const float* __restrict__ bias, unsigned short* __restrict__ Cout,
    int M, int N, int K) {
  __shared__ unsigned short sA[128 * 32];
  __shared__ unsigned short sB[128 * 32];
  const int tid = threadIdx.x;
  const int lane = tid & 63;
  const int wave = tid >> 6;
  const int wr = wave >> 1, wc = wave & 1;
  const int m0 = blockIdx.x * 128, n0 = blockIdx.y * 128;

  f32x4 acc[4][4] = {};

  const int srow = lane >> 2;          // 0..15
  const int scol = (lane & 3) * 8;     // 0/8/16/24 (elements)
  const int c0 = wave * 2, c1 = wave * 2 + 1;
  const float* Af0 = A + (size_t)(m0 + c0 * 16 + srow) * K + scol;
  const float* Af1 = A + (size_t)(m0 + c1 * 16 + srow) * K + scol;
  const unsigned short* Br0 = Bt + (size_t)(n0 + c0 * 16 + srow) * K + scol;
  const unsigned short* Br1 = Bt + (size_t)(n0 + c1 * 16 + srow) * K + scol;

  // prologue: load A regs for kk=0
  float4 a00 = *reinterpret_cast<const float4*>(Af0);
  float4 a01 = *reinterpret_cast<const float4*>(Af0 + 4);
  float4 a10 = *reinterpret_cast<const float4*>(Af1);
  float4 a11 = *reinterpret_cast<const float4*>(Af1 + 4);

  for (int kk = 0; kk < K; kk += 32) {
    __syncthreads();
    // pack current A regs -> bf16, write to LDS
    {
      union { unsigned int u[4]; bf16x8 v; } p;
      p.u[0] = cvt_pk_bf16(a00.x, a00.y);
      p.u[1] = cvt_pk_bf16(a00.z, a00.w);
      p.u[2] = cvt_pk_bf16(a01.x, a01.y);
      p.u[3] = cvt_pk_bf16(a01.z, a01.w);
      *reinterpret_cast<bf16x8*>(&sA[c0 * 512 + srow * 32 + scol]) = p.v;
      p.u[0] = cvt_pk_bf16(a10.x, a10.y);
      p.u[1] = cvt_pk_bf16(a10.z, a10.w);
      p.u[2] = cvt_pk_bf16(a11.x, a11.y);
      p.u[3] = cvt_pk_bf16(a11.z, a11.w);
      *reinterpret_cast<bf16x8*>(&sA[c1 * 512 + srow * 32 + scol]) = p.v;
    }
    gload_lds16(Br0 + kk, &sB[c0 * 512]);
    gload_lds16(Br1 + kk, &sB[c1 * 512]);
    __syncthreads();
    // prefetch next A tile (hides under compute)
    if (kk + 32 < K) {
      a00 = *reinterpret_cast<const float4*>(Af0 + kk + 32);
      a01 = *reinterpret_cast<const float4*>(Af0 + kk + 36);
      a10 = *reinterpret_cast<const float4*>(Af1 + kk + 32);
      a11 = *reinterpret_cast<const float4*>(Af1 + kk + 36);
    }
    bf16x8 af[4], bfr[4];
#pragma unroll
    for (int mi = 0; mi < 4; ++mi)
      af[mi] = *reinterpret_cast<const bf16x8*>(
          &sA[(wr * 64 + mi * 16 + (lane & 15)) * 32 + (lane >> 4) * 8]);
#pragma unroll
    for (int ni = 0; ni < 4; ++ni)
      bfr[ni] = *reinterpret_cast<const bf16x8*>(
          &sB[(wc * 64 + ni * 16 + (lane & 15)) * 32 + (lane >> 4) * 8]);
#pragma unroll
    for (int mi = 0; mi < 4; ++mi)
#pragma unroll
      for (int ni = 0; ni < 4; ++ni)
        acc[mi][ni] = __builtin_amdgcn_mfma_f32_16x16x32_bf16(
            af[mi], bfr[ni], acc[mi][ni], 0, 0, 0);
  }

  const int crow0 = m0 + wr * 64 + (lane >> 4) * 4;
  const int ccol0 = n0 + wc * 64 + (lane & 15);
#pragma unroll
  for (int mi = 0; mi < 4; ++mi) {
#pragma unroll
    for (int ni = 0; ni < 4; ++ni) {
      const int gcol = ccol0 + ni * 16;
      const float bv = bias[gcol];
#pragma unroll
      for (int r = 0; r < 4; ++r) {
        const int grow = crow0 + mi * 16 + r;
        Cout[(size_t)grow * N + gcol] = f2bf(tanh_fast(acc[mi][ni][r] + bv));
      }
    }
  }
}

// ---------- GEMM2: logits = A16 @ Bt^T + bias -> f32 ----------
__global__ __launch_bounds__(256, 2) void gemm_tt(
    const unsigned short* __restrict__ A, const unsigned short* __restrict__ Bt,
    const float* __restrict__ bias, float* __restrict__ Cout,
    int M, int N, int K) {
  __shared__ unsigned short sA[128 * 32];
  __shared__ unsigned short sB[128 * 32];
  const int tid = threadIdx.x;
  const int lane = tid & 63;
  const int wave = tid >> 6;
  const int wr = wave >> 1, wc = wave & 1;
  const int m0 = blockIdx.x * 128, n0 = blockIdx.y * 128;

  f32x4 acc[4][4] = {};

  const int srow = lane >> 2;
  const int scol = (lane & 3) * 8;
  const int c0 = wave * 2, c1 = wave * 2 + 1;
  const unsigned short* Ar0 = A + (size_t)(m0 + c0 * 16 + srow) * K + scol;
  const unsigned short* Ar1 = A + (size_t)(m0 + c1 * 16 + srow) * K + scol;
  const unsigned short* Br0 = Bt + (size_t)(n0 + c0 * 16 + srow) * K + scol;
  const unsigned short* Br1 = Bt + (size_t)(n0 + c1 * 16 + srow) * K + scol;

  for (int kk = 0; kk < K; kk += 32) {
    __syncthreads();
    gload_lds16(Ar0 + kk, &sA[c0 * 512]);
    gload_lds16(Ar1 + kk, &sA[c1 * 512]);
    gload_lds16(Br0 + kk, &sB[c0 * 512]);
    gload_lds16(Br1 + kk, &sB[c1 * 512]);
    __syncthreads();
    bf16x8 af[4], bfr[4];
#pragma unroll
    for (int mi = 0; mi < 4; ++mi)
      af[mi] = *reinterpret_cast<const bf16x8*>(
          &sA[(wr * 64 + mi * 16 + (lane & 15)) * 32 + (lane >> 4) * 8]);
#pragma unroll
    for (int ni = 0; ni < 4; ++ni)
      bfr[ni] = *reinterpret_cast<const bf16x8*>(
          &sB[(wc * 64 + ni * 16 + (lane & 15)) * 32 + (lane >> 4) * 8]);
#pragma unroll
    for (int mi = 0; mi < 4; ++mi)
#pragma unroll
      for (int ni = 0; ni < 4; ++ni)
        acc[mi][ni] = __builtin_amdgcn_mfma_f32_16x16x32_bf16(
            af[mi], bfr[ni], acc[mi][ni], 0, 0, 0);
  }

  const int crow0 = m0 + wr * 64 + (lane >> 4) * 4;
  const int ccol0 = n0 + wc * 64 + (lane & 15);
#pragma unroll
  for (int mi = 0; mi < 4; ++mi) {
#pragma unroll
    for (int ni = 0; ni < 4; ++ni) {
      const int gcol = ccol0 + ni * 16;
      const float bv = bias[gcol];
#pragma unroll
      for (int r = 0; r < 4; ++r) {
        const int grow = crow0 + mi * 16 + r;
        Cout[(size_t)grow * N + gcol] = acc[mi][ni][r] + bv;
      }
    }
  }
}

// ---------- windowed softmax -> jw [B][128][128] bf16 ----------
__global__ __launch_bounds__(256) void wsoftmax_kernel(
    const float* __restrict__ logits, const float* __restrict__ p0buf,
    unsigned short* __restrict__ jwout) {
  const int lane = threadIdx.x & 63;
  const int wave = threadIdx.x >> 6;
  const int row = blockIdx.x * 4 + wave;  // row = b*128 + i, < 32768
  const int i = row & 127;
  const float* lrow = logits + (size_t)row * 256 + (128 - i);
  const float v0 = lrow[lane];
  const float v1 = lrow[lane + 64];
  float mx = fmaxf(v0, v1);
#pragma unroll
  for (int off = 32; off > 0; off >>= 1) mx = fmaxf(mx, __shfl_xor(mx, off));
  const float e0 = __expf(v0 - mx);
  const float e1 = __expf(v1 - mx);
  float s = e0 + e1;
#pragma unroll
  for (int off = 32; off > 0; off >>= 1) s += __shfl_xor(s, off);
  const float scale = p0buf[1] / s;  // (1-p0)/sum
  unsigned short* orow = jwout + (size_t)row * 128;
  orow[lane] = f2bf(e0 * scale);
  orow[lane + 64] = f2bf(e1 * scale);
}

// ---------- fused HMM forward: in-LDS emission transpose + MFMA recursion ----
// Phase 0: waves 1..3 stage emission[b] into LDS as se[t][half*128+m*8+nt]
//          (4x4 register transpose), wave 0 builds jw B-frags meanwhile.
// Phase 1 (wave 0 only): g'[k] = (sum_jj g[jj]*jw[jj,k])*e0[k,t] + g[k]*p0*e1[k,t]
#define SE_STRIDE 264  // floats; 1056B row pitch (16B aligned), breaks pow2 banks
__global__ __launch_bounds__(256, 1) void forward_fused(
    const unsigned short* __restrict__ jwb,   // [B][128][128] bf16
    const float* __restrict__ emission,       // [B][256][64]
    const float* __restrict__ p0buf, const int* __restrict__ slen_p,
    const int* __restrict__ tlen_p, float* __restrict__ out) {
  __shared__ __align__(16) float se[64 * SE_STRIDE];
  __shared__ __align__(16) unsigned short gl16[128];
  const int b = blockIdx.x;
  const int tid = threadIdx.x;
  const float* eb = emission + (size_t)b * 16384;

  bf16x8 bfr[4][8];
  const int l = tid & 63;
  const int m = l & 15;
  const int q = l >> 4;

  if (tid >= 64) {
    // ---- transpose emission[b] ([256][64] -> se[t][perm(k)]) ----
    // 1024 tasks: t0c(4b) | m(4b) | nt0sel(1b) | half(1b); 192 helper threads
#pragma unroll
    for (int it = 0; it < 6; ++it) {
      const int tau = (tid - 64) + 192 * it;
      if (tau < 1024) {
        const int t0 = (tau & 15) * 4;
        const int mm = (tau >> 4) & 15;
        const int nt0 = ((tau >> 8) & 1) * 4;
        const int half = (tau >> 9) & 1;
        const int kbase = half * 128 + nt0 * 16 + mm;
        const float4 v0 = *reinterpret_cast<const float4*>(&eb[(size_t)(kbase) * 64 + t0]);
        const float4 v1 = *reinterpret_cast<const float4*>(&eb[(size_t)(kbase + 16) * 64 + t0]);
        const float4 v2 = *reinterpret_cast<const float4*>(&eb[(size_t)(kbase + 32) * 64 + t0]);
        const float4 v3 = *reinterpret_cast<const float4*>(&eb[(size_t)(kbase + 48) * 64 + t0]);
        const int jinv0 = half * 128 + mm * 8 + nt0;
        float* d = &se[(size_t)t0 * SE_STRIDE + jinv0];
        *reinterpret_cast<float4*>(d) = (float4){v0.x, v1.x, v2.x, v3.x};
        *reinterpret_cast<float4*>(d + SE_STRIDE) = (float4){v0.y, v1.y, v2.y, v3.y};
        *reinterpret_cast<float4*>(d + 2 * SE_STRIDE) = (float4){v0.z, v1.z, v2.z, v3.z};
        *reinterpret_cast<float4*>(d + 3 * SE_STRIDE) = (float4){v0.w, v1.w, v2.w, v3.w};
      }
    }
  } else {
    // ---- wave 0: build jw B-frags: bfr[kt][nt][j] = jw[kt*32+q*8+j][nt*16+m]
    const unsigned short* jwt = jwb + (size_t)b * 16384;
#pragma unroll
    for (int kt = 0; kt < 4; ++kt) {
      const int r0 = kt * 32 + q * 8;
#pragma unroll
      for (int nt = 0; nt < 8; ++nt) {
        const int c = nt * 16 + m;
        bf16x8 v;
#pragma unroll
        for (int j = 0; j < 8; ++j) v[j] = (short)jwt[(size_t)(r0 + j) * 128 + c];
        bfr[kt][nt] = v;
      }
    }
  }
  __syncthreads();
  if (tid >= 64) return;  // helpers done; wave 0 continues alone

  const float p0 = p0buf[0];
  const int S = slen_p[b];
  const int T = tlen_p[b];

  // ---- init g0[k] = e0[k,0] + e1[k,0]
  float gown[8];
  {
    const float4 i0a = *reinterpret_cast<const float4*>(&se[m * 8]);
    const float4 i0b = *reinterpret_cast<const float4*>(&se[m * 8 + 4]);
    const float4 i1a = *reinterpret_cast<const float4*>(&se[128 + m * 8]);
    const float4 i1b = *reinterpret_cast<const float4*>(&se[128 + m * 8 + 4]);
    gown[0] = i0a.x + i1a.x; gown[1] = i0a.y + i1a.y;
    gown[2] = i0a.z + i1a.z; gown[3] = i0a.w + i1a.w;
    gown[4] = i0b.x + i1b.x; gown[5] = i0b.y + i1b.y;
    gown[6] = i0b.z + i1b.z; gown[7] = i0b.w + i1b.w;
  }
  gl16[(2 * q) * 16 + m]     = f2bf(gown[2 * q]);
  gl16[(2 * q + 1) * 16 + m] = f2bf(gown[2 * q + 1]);

  for (int t = 1; t < S; ++t) {
    const float* st = &se[(size_t)t * SE_STRIDE];
    const float4 pe0a = *reinterpret_cast<const float4*>(&st[m * 8]);
    const float4 pe0b = *reinterpret_cast<const float4*>(&st[m * 8 + 4]);
    const float4 pe1a = *reinterpret_cast<const float4*>(&st[128 + m * 8]);
    const float4 pe1b = *reinterpret_cast<const float4*>(&st[128 + m * 8 + 4]);
    const float e0[8] = {pe0a.x, pe0a.y, pe0a.z, pe0a.w, pe0b.x, pe0b.y, pe0b.z, pe0b.w};
    const float e1[8] = {pe1a.x, pe1a.y, pe1a.z, pe1a.w, pe1b.x, pe1b.y, pe1b.z, pe1b.w};
    // self-term off the MFMA critical path
    float h[8];
#pragma unroll
    for (int nt = 0; nt < 8; ++nt) h[nt] = gown[nt] * (p0 * e1[nt]);
    // A-frags: g octets from LDS (bf16 broadcast reads)
    bf16x8 af[4];
#pragma unroll
    for (int kt = 0; kt < 4; ++kt)
      af[kt] = *reinterpret_cast<const bf16x8*>(&gl16[kt * 32 + q * 8]);
    // matvec on the matrix pipe: 8 n-tiles x 4 chained k-tiles
    f32x4 acc[8];
#pragma unroll
    for (int nt = 0; nt < 8; ++nt) {
      f32x4 a = __builtin_amdgcn_mfma_f32_16x16x32_bf16(
          af[0], bfr[0][nt], (f32x4){0.f, 0.f, 0.f, 0.f}, 0, 0, 0);
      a = __builtin_amdgcn_mfma_f32_16x16x32_bf16(af[1], bfr[1][nt], a, 0, 0, 0);
      a = __builtin_amdgcn_mfma_f32_16x16x32_bf16(af[2], bfr[2][nt], a, 0, 0, 0);
      acc[nt] = __builtin_amdgcn_mfma_f32_16x16x32_bf16(af[3], bfr[3][nt], a, 0, 0, 0);
    }
#pragma unroll
    for (int nt = 0; nt < 8; ++nt) gown[nt] = fmaf(acc[nt][0], e0[nt], h[nt]);
    gl16[(2 * q) * 16 + m]     = f2bf(gown[2 * q]);
    gl16[(2 * q + 1) * 16 + m] = f2bf(gown[2 * q + 1]);
  }

  // masked sum over k<T, reduce across 16 m-lanes (q-groups identical)
  float val = 0.f;
#pragma unroll
  for (int nt = 0; nt < 8; ++nt)
    if (nt * 16 + m < T) val += gown[nt];
#pragma unroll
  for (int off = 1; off < 16; off <<= 1) val += __shfl_xor(val, off);
  if (l == 0) out[b] = logf(val + 1e-29f);
}

// ---------- launch ----------
extern "C" void kernel_launch(void* const* d_in, const int* in_sizes, int n_in,
                              void* d_out, int out_size, void* d_ws, size_t ws_size,
                              hipStream_t stream) {
  const float* y_hidden = (const float*)d_in[0];   // [256,128,512]
  const float* y_null   = (const float*)d_in[1];   // [1,1,512]
  const float* W_trans  = (const float*)d_in[2];   // [512,512]
  const float* b_trans  = (const float*)d_in[3];   // [512]
  const float* W_jump   = (const float*)d_in[4];   // [512,257]
  const float* b_jump   = (const float*)d_in[5];   // [257]
  const float* W_p0     = (const float*)d_in[6];   // [512,1]
  const float* b_p0     = (const float*)d_in[7];   // [1]
  const float* emission = (const float*)d_in[8];   // [256,256,64]
  const int* slen = (const int*)d_in[9];
  const int* tlen = (const int*)d_in[10];
  float* out = (float*)d_out;

  char* ws = (char*)d_ws;
  float* logits         = (float*)ws;                        // 33,554,432 B
  unsigned short* ts16  = (unsigned short*)(ws + 33554432);  // 33,554,432 B
  unsigned short* wt16t = (unsigned short*)(ws + 67108864);  // 524,288 B
  unsigned short* wj16t = (unsigned short*)(ws + 67633152);  // 262,144 B
  float* p0buf          = (float*)(ws + 67895296);           // 256 B
  unsigned short* jwb16 = (unsigned short*)(ws + 67895552);  // 8,388,608 B

  cvt_transpose_kernel<<<dim3((512 * 512 + 255) / 256), dim3(256), 0, stream>>>(
      W_trans, wt16t, 512, 512, 512);
  cvt_transpose_kernel<<<dim3((512 * 256 + 255) / 256), dim3(256), 0, stream>>>(
      W_jump, wj16t, 512, 256, 257);
  p0_kernel<<<dim3(1), dim3(512), 0, stream>>>(y_null, W_trans, b_trans, W_p0, b_p0, p0buf);

  // GEMM1: ts = tanh(y_f32 @ W_trans + b) -> bf16 (A converted in-kernel)
  gemm_af32<<<dim3(256, 4), dim3(256), 0, stream>>>(y_hidden, wt16t, b_trans, ts16,
                                                    32768, 512, 512);
  // GEMM2: logits = ts @ W_jump[:,0:256] + b -> f32
  gemm_tt<<<dim3(256, 2), dim3(256), 0, stream>>>(ts16, wj16t, b_jump, logits,
                                                  32768, 256, 512);
  wsoftmax_kernel<<<dim3(8192), dim3(256), 0, stream>>>(logits, p0buf, jwb16);
  // fused emission-transpose + HMM forward + masked log-sum
  forward_fused<<<dim3(256), dim3(256), 0, stream>>>(jwb16, emission, p0buf,
                                                     slen, tlen, out);
}

// Round 6
// 118.610 us; speedup vs baseline: 1.2990x; 1.0068x over previous
//
#include <hip/hip_runtime.h>
#include <stdint.h>

// ---------- types ----------
typedef __attribute__((ext_vector_type(8))) short bf16x8;
typedef __attribute__((ext_vector_type(4))) float f32x4;

// ---------- helpers ----------
__device__ __forceinline__ unsigned short f2bf(float f) {
  union { float f; unsigned int u; } un; un.f = f;
  unsigned int r = un.u + 0x7fffu + ((un.u >> 16) & 1u);
  return (unsigned short)(r >> 16);
}

__device__ __forceinline__ float tanh_fast(float x) {
  x = fminf(15.f, fmaxf(-15.f, x));
  float e = __expf(2.f * x);
  return (e - 1.f) / (e + 1.f);
}

__device__ __forceinline__ unsigned int cvt_pk_bf16(float lo, float hi) {
  unsigned int r;
  asm("v_cvt_pk_bf16_f32 %0, %1, %2" : "=v"(r) : "v"(lo), "v"(hi));
  return r;
}

// async global->LDS, 16B per lane. lds dest must be wave-uniform base.
__device__ __forceinline__ void gload_lds16(const void* g, void* l) {
  __builtin_amdgcn_global_load_lds(
      (const __attribute__((address_space(1))) unsigned int*)(unsigned long long)g,
      (__attribute__((address_space(3))) unsigned int*)(unsigned int)(unsigned long long)l,
      16, 0, 0);
}

// Wt[c][r] = bf16(W[r][c]); W is [R][ldW], use first C cols. Wt row-major [C][R].
__global__ __launch_bounds__(256) void cvt_transpose_kernel(
    const float* __restrict__ W, unsigned short* __restrict__ Wt,
    int R, int C, int ldW) {
  int i = blockIdx.x * blockDim.x + threadIdx.x;
  if (i < R * C) {
    int c = i / R, r = i - c * R;
    Wt[(size_t)c * R + r] = f2bf(W[(size_t)r * ldW + c]);
  }
}

// ---------- p0 kernel (null-token path) ----------
__global__ __launch_bounds__(512) void p0_kernel(
    const float* __restrict__ ynull, const float* __restrict__ W_trans,
    const float* __restrict__ b_trans, const float* __restrict__ W_p0,
    const float* __restrict__ b_p0, float* __restrict__ p0buf) {
  __shared__ float red[512];
  const int hh = threadIdx.x;
  float acc = 0.f;
  for (int e = 0; e < 512; ++e) acc = fmaf(ynull[e], W_trans[(size_t)e * 512 + hh], acc);
  const float ts = tanhf(acc + b_trans[hh]);
  red[hh] = ts * W_p0[hh];
  __syncthreads();
  for (int s = 256; s > 0; s >>= 1) {
    if (hh < s) red[hh] += red[hh + s];
    __syncthreads();
  }
  if (hh == 0) {
    const float z = red[0] + b_p0[0];
    const float p0 = 1.f / (1.f + __expf(-z));
    p0buf[0] = p0;
    p0buf[1] = 1.f - p0;
  }
}

// LDS slot swizzle: within each 32-elem (64B) row, 16B slot s of row r holds
// data slot s ^ ((r>>1)&3). Spreads same-parity rows over 4 slots -> 2-way max.

// ---------- GEMM1: C = tanh(Af32 @ Bt^T + bias) -> bf16 ----------
// A [M,K] f32 row-major (converted to bf16 on the fly during staging);
// Bt [N,K] bf16 row-major. 128x128 tile, BK=32, 4 waves.
__global__ __launch_bounds__(256, 2) void gemm_af32(
    const float* __restrict__ A, const unsigned short* __restrict__ Bt,
    const float* __restrict__ bias, unsigned short* __restrict__ Cout,
    int M, int N, int K) {
  __shared__ unsigned short sA[128 * 32];
  __shared__ unsigned short sB[128 * 32];
  const int tid = threadIdx.x;
  const int lane = tid & 63;
  const int wave = tid >> 6;
  const int wr = wave >> 1, wc = wave & 1;
  const int m0 = blockIdx.x * 128, n0 = blockIdx.y * 128;

  f32x4 acc[4][4] = {};

  const int srow = lane >> 2;            // 0..15
  const int sl = lane & 3;               // slot 0..3
  const int scol = sl * 8;               // linear elem col (A global load)
  const int wsz = (srow >> 1) & 3;       // row-swizzle key
  const int scolw = (sl ^ wsz) * 8;      // swizzled slot (LDS write / B source)
  const int c0 = wave * 2, c1 = wave * 2 + 1;
  const float* Af0 = A + (size_t)(m0 + c0 * 16 + srow) * K + scol;
  const float* Af1 = A + (size_t)(m0 + c1 * 16 + srow) * K + scol;
  // B: pre-swizzled global source, linear LDS dest (rule: both-sides-or-neither)
  const unsigned short* Br0 = Bt + (size_t)(n0 + c0 * 16 + srow) * K + scolw;
  const unsigned short* Br1 = Bt + (size_t)(n0 + c1 * 16 + srow) * K + scolw;

  // prologue: load A regs for kk=0
  float4 a00 = *reinterpret_cast<const float4*>(Af0);
  float4 a01 = *reinterpret_cast<const float4*>(Af0 + 4);
  float4 a10 = *reinterpret_cast<const float4*>(Af1);
  float4 a11 = *reinterpret_cast<const float4*>(Af1 + 4);

  // fragment-read swizzle (must match write-side permutation)
  const int r15 = lane & 15;
  const int oslot = (((lane >> 4) ^ ((r15 >> 1) & 3))) * 8;

  for (int kk = 0; kk < K; kk += 32) {
    __syncthreads();
    // pack current A regs -> bf16, write to LDS at swizzled slot
    {
      union { unsigned int u[4]; bf16x8 v; } p;
      p.u[0] = cvt_pk_bf16(a00.x, a00.y);
      p.u[1] = cvt_pk_bf16(a00.z, a00.w);
      p.u[2] = cvt_pk_bf16(a01.x, a01.y);
      p.u[3] = cvt_pk_bf16(a01.z, a01.w);
      *reinterpret_cast<bf16x8*>(&sA[c0 * 512 + srow * 32 + scolw]) = p.v;
      p.u[0] = cvt_pk_bf16(a10.x, a10.y);
      p.u[1] = cvt_pk_bf16(a10.z, a10.w);
      p.u[2] = cvt_pk_bf16(a11.x, a11.y);
      p.u[3] = cvt_pk_bf16(a11.z, a11.w);
      *reinterpret_cast<bf16x8*>(&sA[c1 * 512 + srow * 32 + scolw]) = p.v;
    }
    gload_lds16(Br0 + kk, &sB[c0 * 512]);
    gload_lds16(Br1 + kk, &sB[c1 * 512]);
    __syncthreads();
    // prefetch next A tile (hides under compute)
    if (kk + 32 < K) {
      a00 = *reinterpret_cast<const float4*>(Af0 + kk + 32);
      a01 = *reinterpret_cast<const float4*>(Af0 + kk + 36);
      a10 = *reinterpret_cast<const float4*>(Af1 + kk + 32);
      a11 = *reinterpret_cast<const float4*>(Af1 + kk + 36);
    }
    bf16x8 af[4], bfr[4];
#pragma unroll
    for (int mi = 0; mi < 4; ++mi)
      af[mi] = *reinterpret_cast<const bf16x8*>(
          &sA[(wr * 64 + mi * 16 + r15) * 32 + oslot]);
#pragma unroll
    for (int ni = 0; ni < 4; ++ni)
      bfr[ni] = *reinterpret_cast<const bf16x8*>(
          &sB[(wc * 64 + ni * 16 + r15) * 32 + oslot]);
#pragma unroll
    for (int mi = 0; mi < 4; ++mi)
#pragma unroll
      for (int ni = 0; ni < 4; ++ni)
        acc[mi][ni] = __builtin_amdgcn_mfma_f32_16x16x32_bf16(
            af[mi], bfr[ni], acc[mi][ni], 0, 0, 0);
  }

  const int crow0 = m0 + wr * 64 + (lane >> 4) * 4;
  const int ccol0 = n0 + wc * 64 + r15;
#pragma unroll
  for (int mi = 0; mi < 4; ++mi) {
#pragma unroll
    for (int ni = 0; ni < 4; ++ni) {
      const int gcol = ccol0 + ni * 16;
      const float bv = bias[gcol];
#pragma unroll
      for (int r = 0; r < 4; ++r) {
        const int grow = crow0 + mi * 16 + r;
        Cout[(size_t)grow * N + gcol] = f2bf(tanh_fast(acc[mi][ni][r] + bv));
      }
    }
  }
}

// ---------- GEMM2: logits = A16 @ Bt^T + bias -> f32 ----------
__global__ __launch_bounds__(256, 2) void gemm_tt(
    const unsigned short* __restrict__ A, const unsigned short* __restrict__ Bt,
    const float* __restrict__ bias, float* __restrict__ Cout,
    int M, int N, int K) {
  __shared__ unsigned short sA[128 * 32];
  __shared__ unsigned short sB[128 * 32];
  const int tid = threadIdx.x;
  const int lane = tid & 63;
  const int wave = tid >> 6;
  const int wr = wave >> 1, wc = wave & 1;
  const int m0 = blockIdx.x * 128, n0 = blockIdx.y * 128;

  f32x4 acc[4][4] = {};

  const int srow = lane >> 2;
  const int sl = lane & 3;
  const int wsz = (srow >> 1) & 3;
  const int scolw = (sl ^ wsz) * 8;      // pre-swizzled global source slot
  const int c0 = wave * 2, c1 = wave * 2 + 1;
  const unsigned short* Ar0 = A + (size_t)(m0 + c0 * 16 + srow) * K + scolw;
  const unsigned short* Ar1 = A + (size_t)(m0 + c1 * 16 + srow) * K + scolw;
  const unsigned short* Br0 = Bt + (size_t)(n0 + c0 * 16 + srow) * K + scolw;
  const unsigned short* Br1 = Bt + (size_t)(n0 + c1 * 16 + srow) * K + scolw;

  const int r15 = lane & 15;
  const int oslot = (((lane >> 4) ^ ((r15 >> 1) & 3))) * 8;

  for (int kk = 0; kk < K; kk += 32) {
    __syncthreads();
    gload_lds16(Ar0 + kk, &sA[c0 * 512]);
    gload_lds16(Ar1 + kk, &sA[c1 * 512]);
    gload_lds16(Br0 + kk, &sB[c0 * 512]);
    gload_lds16(Br1 + kk, &sB[c1 * 512]);
    __syncthreads();
    bf16x8 af[4], bfr[4];
#pragma unroll
    for (int mi = 0; mi < 4; ++mi)
      af[mi] = *reinterpret_cast<const bf16x8*>(
          &sA[(wr * 64 + mi * 16 + r15) * 32 + oslot]);
#pragma unroll
    for (int ni = 0; ni < 4; ++ni)
      bfr[ni] = *reinterpret_cast<const bf16x8*>(
          &sB[(wc * 64 + ni * 16 + r15) * 32 + oslot]);
#pragma unroll
    for (int mi = 0; mi < 4; ++mi)
#pragma unroll
      for (int ni = 0; ni < 4; ++ni)
        acc[mi][ni] = __builtin_amdgcn_mfma_f32_16x16x32_bf16(
            af[mi], bfr[ni], acc[mi][ni], 0, 0, 0);
  }

  const int crow0 = m0 + wr * 64 + (lane >> 4) * 4;
  const int ccol0 = n0 + wc * 64 + r15;
#pragma unroll
  for (int mi = 0; mi < 4; ++mi) {
#pragma unroll
    for (int ni = 0; ni < 4; ++ni) {
      const int gcol = ccol0 + ni * 16;
      const float bv = bias[gcol];
#pragma unroll
      for (int r = 0; r < 4; ++r) {
        const int grow = crow0 + mi * 16 + r;
        Cout[(size_t)grow * N + gcol] = acc[mi][ni][r] + bv;
      }
    }
  }
}

// ---------- windowed softmax -> jw [B][128][128] bf16 ----------
__global__ __launch_bounds__(256) void wsoftmax_kernel(
    const float* __restrict__ logits, const float* __restrict__ p0buf,
    unsigned short* __restrict__ jwout) {
  const int lane = threadIdx.x & 63;
  const int wave = threadIdx.x >> 6;
  const int row = blockIdx.x * 4 + wave;  // row = b*128 + i, < 32768
  const int i = row & 127;
  const float* lrow = logits + (size_t)row * 256 + (128 - i);
  const float v0 = lrow[lane];
  const float v1 = lrow[lane + 64];
  float mx = fmaxf(v0, v1);
#pragma unroll
  for (int off = 32; off > 0; off >>= 1) mx = fmaxf(mx, __shfl_xor(mx, off));
  const float e0 = __expf(v0 - mx);
  const float e1 = __expf(v1 - mx);
  float s = e0 + e1;
#pragma unroll
  for (int off = 32; off > 0; off >>= 1) s += __shfl_xor(s, off);
  const float scale = p0buf[1] / s;  // (1-p0)/sum
  unsigned short* orow = jwout + (size_t)row * 128;
  orow[lane] = f2bf(e0 * scale);
  orow[lane + 64] = f2bf(e1 * scale);
}

// ---------- fused HMM forward: in-LDS emission transpose + MFMA recursion ----
#define SE_STRIDE 264  // floats; 1056B row pitch (16B aligned), breaks pow2 banks
__global__ __launch_bounds__(256, 1) void forward_fused(
    const unsigned short* __restrict__ jwb,   // [B][128][128] bf16
    const float* __restrict__ emission,       // [B][256][64]
    const float* __restrict__ p0buf, const int* __restrict__ slen_p,
    const int* __restrict__ tlen_p, float* __restrict__ out) {
  __shared__ __align__(16) float se[64 * SE_STRIDE];
  __shared__ __align__(16) unsigned short gl16[128];
  const int b = blockIdx.x;
  const int tid = threadIdx.x;
  const float* eb = emission + (size_t)b * 16384;

  bf16x8 bfr[4][8];
  const int l = tid & 63;
  const int m = l & 15;
  const int q = l >> 4;

  if (tid >= 64) {
    // ---- transpose emission[b] ([256][64] -> se[t][perm(k)]) ----
    // 1024 tasks: t0c(4b) | m(4b) | nt0sel(1b) | half(1b); 192 helper threads
#pragma unroll
    for (int it = 0; it < 6; ++it) {
      const int tau = (tid - 64) + 192 * it;
      if (tau < 1024) {
        const int t0 = (tau & 15) * 4;
        const int mm = (tau >> 4) & 15;
        const int nt0 = ((tau >> 8) & 1) * 4;
        const int half = (tau >> 9) & 1;
        const int kbase = half * 128 + nt0 * 16 + mm;
        const float4 v0 = *reinterpret_cast<const float4*>(&eb[(size_t)(kbase) * 64 + t0]);
        const float4 v1 = *reinterpret_cast<const float4*>(&eb[(size_t)(kbase + 16) * 64 + t0]);
        const float4 v2 = *reinterpret_cast<const float4*>(&eb[(size_t)(kbase + 32) * 64 + t0]);
        const float4 v3 = *reinterpret_cast<const float4*>(&eb[(size_t)(kbase + 48) * 64 + t0]);
        const int jinv0 = half * 128 + mm * 8 + nt0;
        float* d = &se[(size_t)t0 * SE_STRIDE + jinv0];
        *reinterpret_cast<float4*>(d) = (float4){v0.x, v1.x, v2.x, v3.x};
        *reinterpret_cast<float4*>(d + SE_STRIDE) = (float4){v0.y, v1.y, v2.y, v3.y};
        *reinterpret_cast<float4*>(d + 2 * SE_STRIDE) = (float4){v0.z, v1.z, v2.z, v3.z};
        *reinterpret_cast<float4*>(d + 3 * SE_STRIDE) = (float4){v0.w, v1.w, v2.w, v3.w};
      }
    }
  } else {
    // ---- wave 0: build jw B-frags: bfr[kt][nt][j] = jw[kt*32+q*8+j][nt*16+m]
    const unsigned short* jwt = jwb + (size_t)b * 16384;
#pragma unroll
    for (int kt = 0; kt < 4; ++kt) {
      const int r0 = kt * 32 + q * 8;
#pragma unroll
      for (int nt = 0; nt < 8; ++nt) {
        const int c = nt * 16 + m;
        bf16x8 v;
#pragma unroll
        for (int j = 0; j < 8; ++j) v[j] = (short)jwt[(size_t)(r0 + j) * 128 + c];
        bfr[kt][nt] = v;
      }
    }
  }
  __syncthreads();
  if (tid >= 64) return;  // helpers done; wave 0 continues alone

  const float p0 = p0buf[0];
  const int S = slen_p[b];
  const int T = tlen_p[b];

  // ---- init g0[k] = e0[k,0] + e1[k,0]
  float gown[8];
  {
    const float4 i0a = *reinterpret_cast<const float4*>(&se[m * 8]);
    const float4 i0b = *reinterpret_cast<const float4*>(&se[m * 8 + 4]);
    const float4 i1a = *reinterpret_cast<const float4*>(&se[128 + m * 8]);
    const float4 i1b = *reinterpret_cast<const float4*>(&se[128 + m * 8 + 4]);
    gown[0] = i0a.x + i1a.x; gown[1] = i0a.y + i1a.y;
    gown[2] = i0a.z + i1a.z; gown[3] = i0a.w + i1a.w;
    gown[4] = i0b.x + i1b.x; gown[5] = i0b.y + i1b.y;
    gown[6] = i0b.z + i1b.z; gown[7] = i0b.w + i1b.w;
  }
  gl16[(2 * q) * 16 + m]     = f2bf(gown[2 * q]);
  gl16[(2 * q + 1) * 16 + m] = f2bf(gown[2 * q + 1]);

  for (int t = 1; t < S; ++t) {
    const float* st = &se[(size_t)t * SE_STRIDE];
    const float4 pe0a = *reinterpret_cast<const float4*>(&st[m * 8]);
    const float4 pe0b = *reinterpret_cast<const float4*>(&st[m * 8 + 4]);
    const float4 pe1a = *reinterpret_cast<const float4*>(&st[128 + m * 8]);
    const float4 pe1b = *reinterpret_cast<const float4*>(&st[128 + m * 8 + 4]);
    const float e0[8] = {pe0a.x, pe0a.y, pe0a.z, pe0a.w, pe0b.x, pe0b.y, pe0b.z, pe0b.w};
    const float e1[8] = {pe1a.x, pe1a.y, pe1a.z, pe1a.w, pe1b.x, pe1b.y, pe1b.z, pe1b.w};
    // self-term off the MFMA critical path
    float h[8];
#pragma unroll
    for (int nt = 0; nt < 8; ++nt) h[nt] = gown[nt] * (p0 * e1[nt]);
    // A-frags: g octets from LDS (bf16 broadcast reads)
    bf16x8 af[4];
#pragma unroll
    for (int kt = 0; kt < 4; ++kt)
      af[kt] = *reinterpret_cast<const bf16x8*>(&gl16[kt * 32 + q * 8]);
    // matvec on the matrix pipe: 8 n-tiles x 4 chained k-tiles
    f32x4 acc[8];
#pragma unroll
    for (int nt = 0; nt < 8; ++nt) {
      f32x4 a = __builtin_amdgcn_mfma_f32_16x16x32_bf16(
          af[0], bfr[0][nt], (f32x4){0.f, 0.f, 0.f, 0.f}, 0, 0, 0);
      a = __builtin_amdgcn_mfma_f32_16x16x32_bf16(af[1], bfr[1][nt], a, 0, 0, 0);
      a = __builtin_amdgcn_mfma_f32_16x16x32_bf16(af[2], bfr[2][nt], a, 0, 0, 0);
      acc[nt] = __builtin_amdgcn_mfma_f32_16x16x32_bf16(af[3], bfr[3][nt], a, 0, 0, 0);
    }
#pragma unroll
    for (int nt = 0; nt < 8; ++nt) gown[nt] = fmaf(acc[nt][0], e0[nt], h[nt]);
    gl16[(2 * q) * 16 + m]     = f2bf(gown[2 * q]);
    gl16[(2 * q + 1) * 16 + m] = f2bf(gown[2 * q + 1]);
  }

  // masked sum over k<T, reduce across 16 m-lanes (q-groups identical)
  float val = 0.f;
#pragma unroll
  for (int nt = 0; nt < 8; ++nt)
    if (nt * 16 + m < T) val += gown[nt];
#pragma unroll
  for (int off = 1; off < 16; off <<= 1) val += __shfl_xor(val, off);
  if (l == 0) out[b] = logf(val + 1e-29f);
}

// ---------- launch ----------
extern "C" void kernel_launch(void* const* d_in, const int* in_sizes, int n_in,
                              void* d_out, int out_size, void* d_ws, size_t ws_size,
                              hipStream_t stream) {
  const float* y_hidden = (const float*)d_in[0];   // [256,128,512]
  const float* y_null   = (const float*)d_in[1];   // [1,1,512]
  const float* W_trans  = (const float*)d_in[2];   // [512,512]
  const float* b_trans  = (const float*)d_in[3];   // [512]
  const float* W_jump   = (const float*)d_in[4];   // [512,257]
  const float* b_jump   = (const float*)d_in[5];   // [257]
  const float* W_p0     = (const float*)d_in[6];   // [512,1]
  const float* b_p0     = (const float*)d_in[7];   // [1]
  const float* emission = (const float*)d_in[8];   // [256,256,64]
  const int* slen = (const int*)d_in[9];
  const int* tlen = (const int*)d_in[10];
  float* out = (float*)d_out;

  char* ws = (char*)d_ws;
  float* logits         = (float*)ws;                        // 33,554,432 B
  unsigned short* ts16  = (unsigned short*)(ws + 33554432);  // 33,554,432 B
  unsigned short* wt16t = (unsigned short*)(ws + 67108864);  // 524,288 B
  unsigned short* wj16t = (unsigned short*)(ws + 67633152);  // 262,144 B
  float* p0buf          = (float*)(ws + 67895296);           // 256 B
  unsigned short* jwb16 = (unsigned short*)(ws + 67895552);  // 8,388,608 B

  cvt_transpose_kernel<<<dim3((512 * 512 + 255) / 256), dim3(256), 0, stream>>>(
      W_trans, wt16t, 512, 512, 512);
  cvt_transpose_kernel<<<dim3((512 * 256 + 255) / 256), dim3(256), 0, stream>>>(
      W_jump, wj16t, 512, 256, 257);
  p0_kernel<<<dim3(1), dim3(512), 0, stream>>>(y_null, W_trans, b_trans, W_p0, b_p0, p0buf);

  // GEMM1: ts = tanh(y_f32 @ W_trans + b) -> bf16 (A converted in-kernel)
  gemm_af32<<<dim3(256, 4), dim3(256), 0, stream>>>(y_hidden, wt16t, b_trans, ts16,
                                                    32768, 512, 512);
  // GEMM2: logits = ts @ W_jump[:,0:256] + b -> f32
  gemm_tt<<<dim3(256, 2), dim3(256), 0, stream>>>(ts16, wj16t, b_jump, logits,
                                                  32768, 256, 512);
  wsoftmax_kernel<<<dim3(8192), dim3(256), 0, stream>>>(logits, p0buf, jwb16);
  // fused emission-transpose + HMM forward + masked log-sum
  forward_fused<<<dim3(256), dim3(256), 0, stream>>>(jwb16, emission, p0buf,
                                                     slen, tlen, out);
}

// Round 7
// 116.241 us; speedup vs baseline: 1.3255x; 1.0204x over previous
//
#include <hip/hip_runtime.h>
#include <stdint.h>

// ---------- types ----------
typedef __attribute__((ext_vector_type(8))) short bf16x8;
typedef __attribute__((ext_vector_type(4))) float f32x4;

// ---------- helpers ----------
__device__ __forceinline__ unsigned short f2bf(float f) {
  union { float f; unsigned int u; } un; un.f = f;
  unsigned int r = un.u + 0x7fffu + ((un.u >> 16) & 1u);
  return (unsigned short)(r >> 16);
}

__device__ __forceinline__ float bf2f(unsigned short u) {
  union { unsigned int u; float f; } un; un.u = ((unsigned int)u) << 16;
  return un.f;
}

__device__ __forceinline__ float tanh_fast(float x) {
  x = fminf(15.f, fmaxf(-15.f, x));
  float e = __expf(2.f * x);
  return (e - 1.f) / (e + 1.f);
}

__device__ __forceinline__ unsigned int cvt_pk_bf16(float lo, float hi) {
  unsigned int r;
  asm("v_cvt_pk_bf16_f32 %0, %1, %2" : "=v"(r) : "v"(lo), "v"(hi));
  return r;
}

// async global->LDS, 16B per lane. lds dest must be wave-uniform base.
__device__ __forceinline__ void gload_lds16(const void* g, void* l) {
  __builtin_amdgcn_global_load_lds(
      (const __attribute__((address_space(1))) unsigned int*)(unsigned long long)g,
      (__attribute__((address_space(3))) unsigned int*)(unsigned int)(unsigned long long)l,
      16, 0, 0);
}

// ---------- merged weight transpose+convert ----------
// wt[c*512+r] = bf16(W_trans[r*512+c]);  wj[c*512+r] = bf16(W_jump[r*257+c]), c<256
__global__ __launch_bounds__(256) void cvt_weights(
    const float* __restrict__ Wt_in, const float* __restrict__ Wj_in,
    unsigned short* __restrict__ wt, unsigned short* __restrict__ wj) {
  const int i = blockIdx.x * 256 + threadIdx.x;
  if (i < 512 * 512) {
    const int c = i >> 9, r = i & 511;
    wt[i] = f2bf(Wt_in[(size_t)r * 512 + c]);
  } else {
    const int j = i - 512 * 512;  // < 512*256
    const int c = j >> 9, r = j & 511;
    wj[j] = f2bf(Wj_in[(size_t)r * 257 + c]);
  }
}

// ---------- p0 kernel (null-token path) ----------
__global__ __launch_bounds__(512) void p0_kernel(
    const float* __restrict__ ynull, const float* __restrict__ W_trans,
    const float* __restrict__ b_trans, const float* __restrict__ W_p0,
    const float* __restrict__ b_p0, float* __restrict__ p0buf) {
  __shared__ float red[512];
  const int hh = threadIdx.x;
  float acc = 0.f;
  for (int e = 0; e < 512; ++e) acc = fmaf(ynull[e], W_trans[(size_t)e * 512 + hh], acc);
  const float ts = tanhf(acc + b_trans[hh]);
  red[hh] = ts * W_p0[hh];
  __syncthreads();
  for (int s = 256; s > 0; s >>= 1) {
    if (hh < s) red[hh] += red[hh + s];
    __syncthreads();
  }
  if (hh == 0) {
    const float z = red[0] + b_p0[0];
    const float p0 = 1.f / (1.f + __expf(-z));
    p0buf[0] = p0;
    p0buf[1] = 1.f - p0;
  }
}

// LDS slot swizzle: 16B slot s of 64B row r holds data slot s ^ ((r>>1)&3).

// ---------- GEMM1: C = tanh(Af32 @ Bt^T + bias) -> bf16 ----------
// 2-phase double-buffered: stage tile t+1 while computing tile t.
__global__ __launch_bounds__(256, 2) void gemm_af32(
    const float* __restrict__ A, const unsigned short* __restrict__ Bt,
    const float* __restrict__ bias, unsigned short* __restrict__ Cout,
    int M, int N, int K) {
  __shared__ unsigned short sA[2][128 * 32];
  __shared__ unsigned short sB[2][128 * 32];
  const int tid = threadIdx.x;
  const int lane = tid & 63;
  const int wave = tid >> 6;
  const int wr = wave >> 1, wc = wave & 1;
  const int m0 = blockIdx.x * 128, n0 = blockIdx.y * 128;

  f32x4 acc[4][4] = {};

  const int srow = lane >> 2;
  const int sl = lane & 3;
  const int scol = sl * 8;
  const int wsz = (srow >> 1) & 3;
  const int scolw = (sl ^ wsz) * 8;
  const int c0 = wave * 2, c1 = wave * 2 + 1;
  const float* Af0 = A + (size_t)(m0 + c0 * 16 + srow) * K + scol;
  const float* Af1 = A + (size_t)(m0 + c1 * 16 + srow) * K + scol;
  const unsigned short* Br0 = Bt + (size_t)(n0 + c0 * 16 + srow) * K + scolw;
  const unsigned short* Br1 = Bt + (size_t)(n0 + c1 * 16 + srow) * K + scolw;

  const int r15 = lane & 15;
  const int oslot = ((lane >> 4) ^ ((r15 >> 1) & 3)) * 8;
  const int nt = K >> 5;  // 16

  auto writeA = [&](int bi, const float4& v00, const float4& v01,
                    const float4& v10, const float4& v11) {
    union { unsigned int u[4]; bf16x8 v; } p;
    p.u[0] = cvt_pk_bf16(v00.x, v00.y);
    p.u[1] = cvt_pk_bf16(v00.z, v00.w);
    p.u[2] = cvt_pk_bf16(v01.x, v01.y);
    p.u[3] = cvt_pk_bf16(v01.z, v01.w);
    *reinterpret_cast<bf16x8*>(&sA[bi][c0 * 512 + srow * 32 + scolw]) = p.v;
    p.u[0] = cvt_pk_bf16(v10.x, v10.y);
    p.u[1] = cvt_pk_bf16(v10.z, v10.w);
    p.u[2] = cvt_pk_bf16(v11.x, v11.y);
    p.u[3] = cvt_pk_bf16(v11.z, v11.w);
    *reinterpret_cast<bf16x8*>(&sA[bi][c1 * 512 + srow * 32 + scolw]) = p.v;
  };
  auto stageB = [&](int bi, int t) {
    gload_lds16(Br0 + t * 32, &sB[bi][c0 * 512]);
    gload_lds16(Br1 + t * 32, &sB[bi][c1 * 512]);
  };
  auto compute = [&](int bi) {
    bf16x8 af[4], bfr[4];
#pragma unroll
    for (int mi = 0; mi < 4; ++mi)
      af[mi] = *reinterpret_cast<const bf16x8*>(
          &sA[bi][(wr * 64 + mi * 16 + r15) * 32 + oslot]);
#pragma unroll
    for (int ni = 0; ni < 4; ++ni)
      bfr[ni] = *reinterpret_cast<const bf16x8*>(
          &sB[bi][(wc * 64 + ni * 16 + r15) * 32 + oslot]);
#pragma unroll
    for (int mi = 0; mi < 4; ++mi)
#pragma unroll
      for (int ni = 0; ni < 4; ++ni)
        acc[mi][ni] = __builtin_amdgcn_mfma_f32_16x16x32_bf16(
            af[mi], bfr[ni], acc[mi][ni], 0, 0, 0);
  };

  // prologue: X=A(0), Y=A(1); stage tile 0 into buf0
  float4 x0 = *reinterpret_cast<const float4*>(Af0);
  float4 x1 = *reinterpret_cast<const float4*>(Af0 + 4);
  float4 x2 = *reinterpret_cast<const float4*>(Af1);
  float4 x3 = *reinterpret_cast<const float4*>(Af1 + 4);
  float4 y0 = *reinterpret_cast<const float4*>(Af0 + 32);
  float4 y1 = *reinterpret_cast<const float4*>(Af0 + 36);
  float4 y2 = *reinterpret_cast<const float4*>(Af1 + 32);
  float4 y3 = *reinterpret_cast<const float4*>(Af1 + 36);
  writeA(0, x0, x1, x2, x3);
  stageB(0, 0);
  __syncthreads();

  for (int t = 0; t < nt; t += 2) {
    // ---- iter t (compute buf0): stage t+1 (regs Y) -> buf1; load A(t+2) -> X
    if (t + 1 < nt) {
      writeA(1, y0, y1, y2, y3);
      stageB(1, t + 1);
    }
    if (t + 2 < nt) {
      x0 = *reinterpret_cast<const float4*>(Af0 + (t + 2) * 32);
      x1 = *reinterpret_cast<const float4*>(Af0 + (t + 2) * 32 + 4);
      x2 = *reinterpret_cast<const float4*>(Af1 + (t + 2) * 32);
      x3 = *reinterpret_cast<const float4*>(Af1 + (t + 2) * 32 + 4);
    }
    compute(0);
    __syncthreads();
    // ---- iter t+1 (compute buf1): stage t+2 (regs X) -> buf0; load A(t+3) -> Y
    if (t + 2 < nt) {
      writeA(0, x0, x1, x2, x3);
      stageB(0, t + 2);
    }
    if (t + 3 < nt) {
      y0 = *reinterpret_cast<const float4*>(Af0 + (t + 3) * 32);
      y1 = *reinterpret_cast<const float4*>(Af0 + (t + 3) * 32 + 4);
      y2 = *reinterpret_cast<const float4*>(Af1 + (t + 3) * 32);
      y3 = *reinterpret_cast<const float4*>(Af1 + (t + 3) * 32 + 4);
    }
    if (t + 1 < nt) compute(1);
    __syncthreads();
  }

  const int crow0 = m0 + wr * 64 + (lane >> 4) * 4;
  const int ccol0 = n0 + wc * 64 + r15;
#pragma unroll
  for (int mi = 0; mi < 4; ++mi) {
#pragma unroll
    for (int ni = 0; ni < 4; ++ni) {
      const int gcol = ccol0 + ni * 16;
      const float bv = bias[gcol];
#pragma unroll
      for (int r = 0; r < 4; ++r) {
        const int grow = crow0 + mi * 16 + r;
        Cout[(size_t)grow * N + gcol] = f2bf(tanh_fast(acc[mi][ni][r] + bv));
      }
    }
  }
}

// ---------- GEMM2: logits16 = A16 @ Bt^T + bias -> bf16 ----------
// 2-phase double-buffered, all staging via global_load_lds.
__global__ __launch_bounds__(256, 2) void gemm_tt(
    const unsigned short* __restrict__ A, const unsigned short* __restrict__ Bt,
    const float* __restrict__ bias, unsigned short* __restrict__ Cout,
    int M, int N, int K) {
  __shared__ unsigned short sA[2][128 * 32];
  __shared__ unsigned short sB[2][128 * 32];
  const int tid = threadIdx.x;
  const int lane = tid & 63;
  const int wave = tid >> 6;
  const int wr = wave >> 1, wc = wave & 1;
  const int m0 = blockIdx.x * 128, n0 = blockIdx.y * 128;

  f32x4 acc[4][4] = {};

  const int srow = lane >> 2;
  const int sl = lane & 3;
  const int wsz = (srow >> 1) & 3;
  const int scolw = (sl ^ wsz) * 8;
  const int c0 = wave * 2, c1 = wave * 2 + 1;
  const unsigned short* Ar0 = A + (size_t)(m0 + c0 * 16 + srow) * K + scolw;
  const unsigned short* Ar1 = A + (size_t)(m0 + c1 * 16 + srow) * K + scolw;
  const unsigned short* Br0 = Bt + (size_t)(n0 + c0 * 16 + srow) * K + scolw;
  const unsigned short* Br1 = Bt + (size_t)(n0 + c1 * 16 + srow) * K + scolw;

  const int r15 = lane & 15;
  const int oslot = ((lane >> 4) ^ ((r15 >> 1) & 3)) * 8;
  const int nt = K >> 5;  // 16

  auto stage = [&](int bi, int t) {
    gload_lds16(Ar0 + t * 32, &sA[bi][c0 * 512]);
    gload_lds16(Ar1 + t * 32, &sA[bi][c1 * 512]);
    gload_lds16(Br0 + t * 32, &sB[bi][c0 * 512]);
    gload_lds16(Br1 + t * 32, &sB[bi][c1 * 512]);
  };
  auto compute = [&](int bi) {
    bf16x8 af[4], bfr[4];
#pragma unroll
    for (int mi = 0; mi < 4; ++mi)
      af[mi] = *reinterpret_cast<const bf16x8*>(
          &sA[bi][(wr * 64 + mi * 16 + r15) * 32 + oslot]);
#pragma unroll
    for (int ni = 0; ni < 4; ++ni)
      bfr[ni] = *reinterpret_cast<const bf16x8*>(
          &sB[bi][(wc * 64 + ni * 16 + r15) * 32 + oslot]);
#pragma unroll
    for (int mi = 0; mi < 4; ++mi)
#pragma unroll
      for (int ni = 0; ni < 4; ++ni)
        acc[mi][ni] = __builtin_amdgcn_mfma_f32_16x16x32_bf16(
            af[mi], bfr[ni], acc[mi][ni], 0, 0, 0);
  };

  stage(0, 0);
  __syncthreads();
  for (int t = 0; t < nt; t += 2) {
    if (t + 1 < nt) stage(1, t + 1);
    compute(0);
    __syncthreads();
    if (t + 2 < nt) stage(0, t + 2);
    if (t + 1 < nt) compute(1);
    __syncthreads();
  }

  const int crow0 = m0 + wr * 64 + (lane >> 4) * 4;
  const int ccol0 = n0 + wc * 64 + r15;
#pragma unroll
  for (int mi = 0; mi < 4; ++mi) {
#pragma unroll
    for (int ni = 0; ni < 4; ++ni) {
      const int gcol = ccol0 + ni * 16;
      const float bv = bias[gcol];
#pragma unroll
      for (int r = 0; r < 4; ++r) {
        const int grow = crow0 + mi * 16 + r;
        Cout[(size_t)grow * N + gcol] = f2bf(acc[mi][ni][r] + bv);
      }
    }
  }
}

// ---------- windowed softmax (bf16 logits) -> jw [B][128][128] bf16 ----------
__global__ __launch_bounds__(256) void wsoftmax_kernel(
    const unsigned short* __restrict__ logits, const float* __restrict__ p0buf,
    unsigned short* __restrict__ jwout) {
  const int lane = threadIdx.x & 63;
  const int wave = threadIdx.x >> 6;
  const int row = blockIdx.x * 4 + wave;  // row = b*128 + i, < 32768
  const int i = row & 127;
  const unsigned short* lrow = logits + (size_t)row * 256 + (128 - i);
  const float v0 = bf2f(lrow[lane]);
  const float v1 = bf2f(lrow[lane + 64]);
  float mx = fmaxf(v0, v1);
#pragma unroll
  for (int off = 32; off > 0; off >>= 1) mx = fmaxf(mx, __shfl_xor(mx, off));
  const float e0 = __expf(v0 - mx);
  const float e1 = __expf(v1 - mx);
  float s = e0 + e1;
#pragma unroll
  for (int off = 32; off > 0; off >>= 1) s += __shfl_xor(s, off);
  const float scale = p0buf[1] / s;  // (1-p0)/sum
  unsigned short* orow = jwout + (size_t)row * 128;
  orow[lane] = f2bf(e0 * scale);
  orow[lane + 64] = f2bf(e1 * scale);
}

// ---------- fused HMM forward: in-LDS emission transpose + MFMA recursion ----
#define SE_STRIDE 264  // floats; 1056B row pitch (16B aligned), breaks pow2 banks
__global__ __launch_bounds__(256, 1) void forward_fused(
    const unsigned short* __restrict__ jwb,   // [B][128][128] bf16
    const float* __restrict__ emission,       // [B][256][64]
    const float* __restrict__ p0buf, const int* __restrict__ slen_p,
    const int* __restrict__ tlen_p, float* __restrict__ out) {
  __shared__ __align__(16) float se[64 * SE_STRIDE];
  __shared__ __align__(16) unsigned short gl16[128];
  const int b = blockIdx.x;
  const int tid = threadIdx.x;
  const float* eb = emission + (size_t)b * 16384;

  bf16x8 bfr[4][8];
  const int l = tid & 63;
  const int m = l & 15;
  const int q = l >> 4;

  if (tid >= 64) {
    // transpose emission[b] ([256][64] -> se[t][half*128+m*8+nt])
#pragma unroll
    for (int it = 0; it < 6; ++it) {
      const int tau = (tid - 64) + 192 * it;
      if (tau < 1024) {
        const int t0 = (tau & 15) * 4;
        const int mm = (tau >> 4) & 15;
        const int nt0 = ((tau >> 8) & 1) * 4;
        const int half = (tau >> 9) & 1;
        const int kbase = half * 128 + nt0 * 16 + mm;
        const float4 v0 = *reinterpret_cast<const float4*>(&eb[(size_t)(kbase) * 64 + t0]);
        const float4 v1 = *reinterpret_cast<const float4*>(&eb[(size_t)(kbase + 16) * 64 + t0]);
        const float4 v2 = *reinterpret_cast<const float4*>(&eb[(size_t)(kbase + 32) * 64 + t0]);
        const float4 v3 = *reinterpret_cast<const float4*>(&eb[(size_t)(kbase + 48) * 64 + t0]);
        const int jinv0 = half * 128 + mm * 8 + nt0;
        float* d = &se[(size_t)t0 * SE_STRIDE + jinv0];
        *reinterpret_cast<float4*>(d) = (float4){v0.x, v1.x, v2.x, v3.x};
        *reinterpret_cast<float4*>(d + SE_STRIDE) = (float4){v0.y, v1.y, v2.y, v3.y};
        *reinterpret_cast<float4*>(d + 2 * SE_STRIDE) = (float4){v0.z, v1.z, v2.z, v3.z};
        *reinterpret_cast<float4*>(d + 3 * SE_STRIDE) = (float4){v0.w, v1.w, v2.w, v3.w};
      }
    }
  } else {
    // wave 0: build jw B-frags: bfr[kt][nt][j] = jw[kt*32+q*8+j][nt*16+m]
    const unsigned short* jwt = jwb + (size_t)b * 16384;
#pragma unroll
    for (int kt = 0; kt < 4; ++kt) {
      const int r0 = kt * 32 + q * 8;
#pragma unroll
      for (int nt = 0; nt < 8; ++nt) {
        const int c = nt * 16 + m;
        bf16x8 v;
#pragma unroll
        for (int j = 0; j < 8; ++j) v[j] = (short)jwt[(size_t)(r0 + j) * 128 + c];
        bfr[kt][nt] = v;
      }
    }
  }
  __syncthreads();
  if (tid >= 64) return;

  const float p0 = p0buf[0];
  const int S = slen_p[b];
  const int T = tlen_p[b];

  float gown[8];
  {
    const float4 i0a = *reinterpret_cast<const float4*>(&se[m * 8]);
    const float4 i0b = *reinterpret_cast<const float4*>(&se[m * 8 + 4]);
    const float4 i1a = *reinterpret_cast<const float4*>(&se[128 + m * 8]);
    const float4 i1b = *reinterpret_cast<const float4*>(&se[128 + m * 8 + 4]);
    gown[0] = i0a.x + i1a.x; gown[1] = i0a.y + i1a.y;
    gown[2] = i0a.z + i1a.z; gown[3] = i0a.w + i1a.w;
    gown[4] = i0b.x + i1b.x; gown[5] = i0b.y + i1b.y;
    gown[6] = i0b.z + i1b.z; gown[7] = i0b.w + i1b.w;
  }
  gl16[(2 * q) * 16 + m]     = f2bf(gown[2 * q]);
  gl16[(2 * q + 1) * 16 + m] = f2bf(gown[2 * q + 1]);

  for (int t = 1; t < S; ++t) {
    const float* st = &se[(size_t)t * SE_STRIDE];
    const float4 pe0a = *reinterpret_cast<const float4*>(&st[m * 8]);
    const float4 pe0b = *reinterpret_cast<const float4*>(&st[m * 8 + 4]);
    const float4 pe1a = *reinterpret_cast<const float4*>(&st[128 + m * 8]);
    const float4 pe1b = *reinterpret_cast<const float4*>(&st[128 + m * 8 + 4]);
    const float e0[8] = {pe0a.x, pe0a.y, pe0a.z, pe0a.w, pe0b.x, pe0b.y, pe0b.z, pe0b.w};
    const float e1[8] = {pe1a.x, pe1a.y, pe1a.z, pe1a.w, pe1b.x, pe1b.y, pe1b.z, pe1b.w};
    float h[8];
#pragma unroll
    for (int nt = 0; nt < 8; ++nt) h[nt] = gown[nt] * (p0 * e1[nt]);
    bf16x8 af[4];
#pragma unroll
    for (int kt = 0; kt < 4; ++kt)
      af[kt] = *reinterpret_cast<const bf16x8*>(&gl16[kt * 32 + q * 8]);
    f32x4 acc[8];
#pragma unroll
    for (int nt = 0; nt < 8; ++nt) {
      f32x4 a = __builtin_amdgcn_mfma_f32_16x16x32_bf16(
          af[0], bfr[0][nt], (f32x4){0.f, 0.f, 0.f, 0.f}, 0, 0, 0);
      a = __builtin_amdgcn_mfma_f32_16x16x32_bf16(af[1], bfr[1][nt], a, 0, 0, 0);
      a = __builtin_amdgcn_mfma_f32_16x16x32_bf16(af[2], bfr[2][nt], a, 0, 0, 0);
      acc[nt] = __builtin_amdgcn_mfma_f32_16x16x32_bf16(af[3], bfr[3][nt], a, 0, 0, 0);
    }
#pragma unroll
    for (int nt = 0; nt < 8; ++nt) gown[nt] = fmaf(acc[nt][0], e0[nt], h[nt]);
    gl16[(2 * q) * 16 + m]     = f2bf(gown[2 * q]);
    gl16[(2 * q + 1) * 16 + m] = f2bf(gown[2 * q + 1]);
  }

  float val = 0.f;
#pragma unroll
  for (int nt = 0; nt < 8; ++nt)
    if (nt * 16 + m < T) val += gown[nt];
#pragma unroll
  for (int off = 1; off < 16; off <<= 1) val += __shfl_xor(val, off);
  if (l == 0) out[b] = logf(val + 1e-29f);
}

// ---------- launch ----------
extern "C" void kernel_launch(void* const* d_in, const int* in_sizes, int n_in,
                              void* d_out, int out_size, void* d_ws, size_t ws_size,
                              hipStream_t stream) {
  const float* y_hidden = (const float*)d_in[0];   // [256,128,512]
  const float* y_null   = (const float*)d_in[1];   // [1,1,512]
  const float* W_trans  = (const float*)d_in[2];   // [512,512]
  const float* b_trans  = (const float*)d_in[3];   // [512]
  const float* W_jump   = (const float*)d_in[4];   // [512,257]
  const float* b_jump   = (const float*)d_in[5];   // [257]
  const float* W_p0     = (const float*)d_in[6];   // [512,1]
  const float* b_p0     = (const float*)d_in[7];   // [1]
  const float* emission = (const float*)d_in[8];   // [256,256,64]
  const int* slen = (const int*)d_in[9];
  const int* tlen = (const int*)d_in[10];
  float* out = (float*)d_out;

  char* ws = (char*)d_ws;
  unsigned short* ts16  = (unsigned short*)ws;               // 33,554,432 B
  unsigned short* lg16  = (unsigned short*)(ws + 33554432);  // 16,777,216 B
  unsigned short* wt16t = (unsigned short*)(ws + 50331648);  // 524,288 B
  unsigned short* wj16t = (unsigned short*)(ws + 50855936);  // 262,144 B
  float* p0buf          = (float*)(ws + 51118080);           // 256 B
  unsigned short* jwb16 = (unsigned short*)(ws + 51118336);  // 8,388,608 B

  cvt_weights<<<dim3(1536), dim3(256), 0, stream>>>(W_trans, W_jump, wt16t, wj16t);
  p0_kernel<<<dim3(1), dim3(512), 0, stream>>>(y_null, W_trans, b_trans, W_p0, b_p0, p0buf);

  // GEMM1: ts = tanh(y_f32 @ W_trans + b) -> bf16
  gemm_af32<<<dim3(256, 4), dim3(256), 0, stream>>>(y_hidden, wt16t, b_trans, ts16,
                                                    32768, 512, 512);
  // GEMM2: logits = ts @ W_jump[:,0:256] + b -> bf16
  gemm_tt<<<dim3(256, 2), dim3(256), 0, stream>>>(ts16, wj16t, b_jump, lg16,
                                                  32768, 256, 512);
  wsoftmax_kernel<<<dim3(8192), dim3(256), 0, stream>>>(lg16, p0buf, jwb16);
  forward_fused<<<dim3(256), dim3(256), 0, stream>>>(jwb16, emission, p0buf,
                                                     slen, tlen, out);
}